// Round 4
// baseline (2327.597 us; speedup 1.0000x reference)
//
#include <hip/hip_runtime.h>
#include <math.h>

#define DIM   1024
#define NE    64
#define BM    64
#define BK    16
#define NT    64            // 1024/16 k-tiles
#define A_BYTES 4096        // 64 rows x 4 float4-slots
#define B_BYTES 20480       // 320 rows x 4 float4-slots
#define TILE_BYTES (A_BYTES + B_BYTES)   // 24576

// global -> LDS direct copy, 16B/lane; LDS dest = wave-uniform base + lane*16.
__device__ __forceinline__ void gload16(const void* gptr, void* lptr) {
  __builtin_amdgcn_global_load_lds(
      (const __attribute__((address_space(1))) unsigned int*)(unsigned long long)gptr,
      (__attribute__((address_space(3))) unsigned int*)(unsigned int)(unsigned long long)lptr,
      16, 0, 0);
}

__global__ __launch_bounds__(512, 4)
void ur_fused(const float* __restrict__ hs,    // [M,1024]
              const float* __restrict__ Wr,    // [64,1024]
              const float* __restrict__ br,    // [64]
              const float* __restrict__ Wu1,   // [256,1024]
              const float* __restrict__ bu1,   // [256]
              const float* __restrict__ Wu2,   // [256]
              const float* __restrict__ bu2,   // [1]
              float* __restrict__ out,         // w[4M] | idx[4M] | k[M]
              int M) {
  __shared__ __align__(16) char smem[2 * TILE_BYTES];   // 48 KB

  const int tid = threadIdx.x;
  const int m0 = blockIdx.x * BM;
  const int r = tid >> 4;   // 0..31 -> tokens 2r, 2r+1
  const int c = tid & 15;   // cols c+16n, n=0..19

  // ---- staging source pointers: slot i = l*512+tid; i<256 -> A, else B ----
  // LDS layout linear: A slot = 4*ta+qs, B slot = 256 + 4*col+qs.
  // Global k-chunk q = qs ^ swz(row) so reads are XOR-addressed (dest linear).
  const float* gp[3];
#pragma unroll
  for (int l = 0; l < 3; ++l) {
    int i = l * 512 + tid;
    if (i < 256) {
      int ta = i >> 2, qs = i & 3;
      int q = qs ^ ((ta >> 1) & 3);
      gp[l] = hs + (size_t)(m0 + ta) * DIM + q * 4;
    } else {
      int j = i - 256;
      int col = j >> 2, qs = j & 3;
      int q = qs ^ ((col >> 1) & 3);
      gp[l] = (col < NE ? Wr + (size_t)col * DIM
                        : Wu1 + (size_t)(col - NE) * DIM) + q * 4;
    }
  }
  const unsigned wb = (unsigned)(tid & ~63) * 16u;   // wave-uniform LDS base part

  float acc[2][20];
#pragma unroll
  for (int j = 0; j < 2; ++j)
#pragma unroll
    for (int n = 0; n < 20; ++n) acc[j][n] = 0.f;

  const int rsw = r & 3;            // A read swizzle key
  const int csw = (c >> 1) & 3;     // B read swizzle key (wave-constant per thread)

  auto stage = [&](int buf) {
    char* base = smem + buf * TILE_BYTES;
#pragma unroll
    for (int l = 0; l < 3; ++l) {
      gload16(gp[l], base + l * 8192 + wb);
      gp[l] += BK;                  // +64 B along K
    }
  };

  auto compute = [&](int buf) {
    const char* Ab = smem + buf * TILE_BYTES + r * 128;
    const char* Bb = smem + buf * TILE_BYTES + A_BYTES + c * 64;
#pragma unroll
    for (int q = 0; q < 4; ++q) {
      float4 av[2];
#pragma unroll
      for (int j = 0; j < 2; ++j)
        av[j] = *reinterpret_cast<const float4*>(Ab + j * 64 + ((q ^ rsw) << 4));
      const int qb = (q ^ csw) << 4;
#pragma unroll
      for (int n = 0; n < 20; ++n) {
        const float4 bv = *reinterpret_cast<const float4*>(Bb + n * 1024 + qb);
#pragma unroll
        for (int j = 0; j < 2; ++j) {
          acc[j][n] = fmaf(av[j].x, bv.x, acc[j][n]);
          acc[j][n] = fmaf(av[j].y, bv.y, acc[j][n]);
          acc[j][n] = fmaf(av[j].z, bv.z, acc[j][n]);
          acc[j][n] = fmaf(av[j].w, bv.w, acc[j][n]);
        }
      }
    }
  };

  // ---- double-buffered main loop, counted vmcnt, raw barriers ----
  stage(0);
#pragma unroll 1
  for (int t = 0; t < NT - 1; ++t) {
    stage((t + 1) & 1);                                 // 3 loads in flight
    asm volatile("s_waitcnt vmcnt(3)" ::: "memory");    // tile t resident
    __builtin_amdgcn_s_barrier();
    compute(t & 1);
    asm volatile("" ::: "memory");
    __builtin_amdgcn_s_barrier();                       // readers done
  }
  asm volatile("s_waitcnt vmcnt(0)" ::: "memory");
  __builtin_amdgcn_s_barrier();
  compute((NT - 1) & 1);
  __syncthreads();        // tile buffers dead; overlay epilogue arrays

  // ---- epilogue: bias, GELU, uncertainty dot (overlaid LDS) ----
  float* Lg = reinterpret_cast<float*>(smem);                 // [64][65]
  float* Xp = reinterpret_cast<float*>(smem + 16640);         // [16][65]
  float* Xs = reinterpret_cast<float*>(smem + 16640 + 4160);  // [64]

  float xp[2] = {0.f, 0.f};
#pragma unroll
  for (int n = 0; n < 20; ++n) {
    int col = c + 16 * n;
    if (n < 4) {                     // router cols 0..63
      float bias = br[col];
#pragma unroll
      for (int j = 0; j < 2; ++j) Lg[(2 * r + j) * 65 + col] = acc[j][n] + bias;
    } else {                         // u1 cols 64..319
      int qd = col - NE;
      float w2 = Wu2[qd];
      float b1 = bu1[qd];
#pragma unroll
      for (int j = 0; j < 2; ++j) {
        float h = acc[j][n] + b1;
        float g = 0.5f * h * (1.f + erff(h * 0.70710678118654752440f));
        xp[j] = fmaf(g, w2, xp[j]);
      }
    }
  }
  // partial sums: thread (r,c) contributes to tokens 2r,2r+1 from col-group c
#pragma unroll
  for (int j = 0; j < 2; ++j) Xp[c * 65 + 2 * r + j] = xp[j];
  __syncthreads();

  if (tid < BM) {
    float x = bu2[0];
#pragma unroll
    for (int cc = 0; cc < 16; ++cc) x += Xp[cc * 65 + tid];
    Xs[tid] = x;
  }
  __syncthreads();

  // ---- per-token top-4 + masked softmax: one wave per token ----
  const int wave = tid >> 6;   // 0..7
  const int lane = tid & 63;
  const size_t Moff_i = 4 * (size_t)M;
  const size_t Moff_k = 8 * (size_t)M;

  for (int t = wave; t < BM; t += 8) {
    float cur = Lg[t * 65 + lane];
    float topv[4];
    int topi[4];
#pragma unroll
    for (int s = 0; s < 4; ++s) {
      float mv = cur;
      int mi = lane;
#pragma unroll
      for (int off = 32; off >= 1; off >>= 1) {
        float ov = __shfl_xor(mv, off, 64);
        int oi = __shfl_xor(mi, off, 64);
        if (ov > mv || (ov == mv && oi < mi)) { mv = ov; mi = oi; }
      }
      topv[s] = mv;
      topi[s] = mi;
      if (lane == mi) cur = -INFINITY;   // stable: lowest index wins ties
    }
    if (lane == 0) {
      const int token = m0 + t;
      float x = Xs[t];
      float u = 1.f / (1.f + expf(-x));
      float kf = fmaf(3.f, u, 1.f);
      int kv = (int)rintf(kf);           // round-half-even == jnp.round
      kv = kv < 1 ? 1 : (kv > 4 ? 4 : kv);

      float w[4];
#pragma unroll
      for (int s = 0; s < 4; ++s) w[s] = (s < kv) ? topv[s] : 0.f;
      float mx = fmaxf(fmaxf(w[0], w[1]), fmaxf(w[2], w[3]));
      float e[4], sum = 0.f;
#pragma unroll
      for (int s = 0; s < 4; ++s) { e[s] = expf(w[s] - mx); sum += e[s]; }
      float inv = 1.f / sum;
#pragma unroll
      for (int s = 0; s < 4; ++s) {
        out[(size_t)token * 4 + s] = e[s] * inv;
        out[Moff_i + (size_t)token * 4 + s] = (s < kv) ? (float)topi[s] : -1.0f;
      }
      out[Moff_k + token] = (float)kv;
    }
  }
}

extern "C" void kernel_launch(void* const* d_in, const int* in_sizes, int n_in,
                              void* d_out, int out_size, void* d_ws, size_t ws_size,
                              hipStream_t stream) {
  (void)n_in; (void)d_ws; (void)ws_size; (void)out_size;
  const float* hs  = (const float*)d_in[0];
  const float* Wr  = (const float*)d_in[1];
  const float* br  = (const float*)d_in[2];
  const float* Wu1 = (const float*)d_in[3];
  const float* bu1 = (const float*)d_in[4];
  const float* Wu2 = (const float*)d_in[5];
  const float* bu2 = (const float*)d_in[6];
  float* out = (float*)d_out;

  const int M = in_sizes[0] / DIM;  // 32768
  dim3 grid(M / BM);                // 512 blocks, 2 resident/CU (48 KB LDS)
  dim3 block(512);
  hipLaunchKernelGGL(ur_fused, grid, block, 0, stream,
                     hs, Wr, br, Wu1, bu1, Wu2, bu2, out, M);
}

// Round 5
// 321.605 us; speedup vs baseline: 7.2374x; 7.2374x over previous
//
#include <hip/hip_runtime.h>
#include <math.h>

#define DIM   1024
#define NE    64
#define BM    64
#define BK    32
#define NT    32                 // 1024/32 k-tiles
#define A_BYTES 8192             // 64 tok x 8 float4-slots (linear)
#define B_BYTES 40960            // 320 cols x 8 float4-slots (kq source-swizzled)
#define TILE_BYTES (A_BYTES + B_BYTES)   // 49152

// global -> LDS direct copy, 16B/lane; LDS dest = wave-uniform base + lane*16.
__device__ __forceinline__ void gload16(const void* gptr, void* lptr) {
  __builtin_amdgcn_global_load_lds(
      (const __attribute__((address_space(1))) unsigned int*)(unsigned long long)gptr,
      (__attribute__((address_space(3))) unsigned int*)(unsigned int)(unsigned long long)lptr,
      16, 0, 0);
}

__global__ __launch_bounds__(256)
void ur_fused(const float* __restrict__ hs,    // [M,1024]
              const float* __restrict__ Wr,    // [64,1024]
              const float* __restrict__ br,    // [64]
              const float* __restrict__ Wu1,   // [256,1024]
              const float* __restrict__ bu1,   // [256]
              const float* __restrict__ Wu2,   // [256]
              const float* __restrict__ bu2,   // [1]
              float* __restrict__ out,         // w[4M] | idx[4M] | k[M]
              int M) {
  __shared__ __align__(16) char smem[TILE_BYTES];   // 48 KB single buffer

  const int tid = threadIdx.x;
  const int m0 = blockIdx.x * BM;
  const int r = tid >> 5;        // 0..7  -> tokens 8r..8r+7
  const int c = tid & 31;        // 0..31 -> cols c+32n, n=0..9

  // ---- staging bases (slot i = 256l + tid; A: l=0..1, B: l=0..9) ----
  // A slot: ta = i>>3 (l adds 32), kq = tid&7; LDS linear, global linear.
  // B slot: col = (tid>>3)+32l, kq = tid&7; global k-chunk = kq ^ (col&7)
  //         (col&7 == (tid>>3)&7, l-invariant) so LDS stays linear (m173).
  const int t8 = tid >> 3, k8 = tid & 7;
  const int kqg = k8 ^ (t8 & 7);
  const char* pA = (const char*)(hs + (size_t)(m0 + t8) * DIM) + (k8 << 4);
  const char* pB0 = (const char*)(Wr + (size_t)t8 * DIM) + (kqg << 4);
  const char* pB1 = (const char*)(Wu1 + (size_t)t8 * DIM) + (kqg << 4);
  const unsigned wb = (unsigned)(tid & ~63) * 16u;   // wave-uniform LDS lane-0 part

  float acc[8][10];
#pragma unroll
  for (int j = 0; j < 8; ++j)
#pragma unroll
    for (int n = 0; n < 10; ++n) acc[j][n] = 0.f;

  const char* Ab = smem + r * 1024;                  // (8r)*128
  const char* Bb = smem + A_BYTES + c * 128;
  const int csw = c & 7;                             // B read swizzle key

#pragma unroll 1
  for (int t = 0; t < NT; ++t) {
    __syncthreads();   // previous tile's readers done (drains lgkm)
    // A: 2 issues (slots 0..511). 131072 = 32 rows * 4096 B.
    gload16(pA, smem + (0 * 4096 + wb));
    gload16(pA + 131072, smem + (1 * 4096 + wb));
    pA += 128;
    // B: 10 issues (cols (tid>>3)+32l; l<2 from Wr, l>=2 from Wu1)
#pragma unroll
    for (int l = 0; l < 2; ++l)
      gload16(pB0 + l * 131072, smem + A_BYTES + l * 4096 + wb);
#pragma unroll
    for (int l = 2; l < 10; ++l)
      gload16(pB1 + (l - 2) * 131072, smem + A_BYTES + l * 4096 + wb);
    pB0 += 128;
    pB1 += 128;
    __syncthreads();   // drains vmcnt(0): tile resident

#pragma unroll
    for (int kq = 0; kq < 8; ++kq) {
      float4 av[8];
#pragma unroll
      for (int j = 0; j < 8; ++j)   // same-address broadcast within each phase
        av[j] = *reinterpret_cast<const float4*>(Ab + j * 128 + (kq << 4));
      const int qb = (kq ^ csw) << 4;
#pragma unroll
      for (int n = 0; n < 10; ++n) {
        const float4 bv = *reinterpret_cast<const float4*>(Bb + n * 4096 + qb);
#pragma unroll
        for (int j = 0; j < 8; ++j) {
          acc[j][n] = fmaf(av[j].x, bv.x, acc[j][n]);
          acc[j][n] = fmaf(av[j].y, bv.y, acc[j][n]);
          acc[j][n] = fmaf(av[j].z, bv.z, acc[j][n]);
          acc[j][n] = fmaf(av[j].w, bv.w, acc[j][n]);
        }
      }
    }
  }
  __syncthreads();     // tile buffer dead; overlay epilogue arrays

  // ---- epilogue: bias, GELU, uncertainty dot (overlaid LDS) ----
  float* Lg = reinterpret_cast<float*>(smem);                 // [64][65]
  float* Xp = reinterpret_cast<float*>(smem + 16640);         // [32][65]
  float* Xs = reinterpret_cast<float*>(smem + 16640 + 8320);  // [64]

  float xp[8] = {0, 0, 0, 0, 0, 0, 0, 0};
#pragma unroll
  for (int n = 0; n < 10; ++n) {
    int col = c + 32 * n;
    if (n < 2) {                   // router cols 0..63
      float bias = br[col];
#pragma unroll
      for (int j = 0; j < 8; ++j) Lg[(8 * r + j) * 65 + col] = acc[j][n] + bias;
    } else {                       // u1 cols 64..319
      int qd = col - NE;
      float w2 = Wu2[qd];
      float b1 = bu1[qd];
#pragma unroll
      for (int j = 0; j < 8; ++j) {
        float h = acc[j][n] + b1;
        float g = 0.5f * h * (1.f + erff(h * 0.70710678118654752440f));
        xp[j] = fmaf(g, w2, xp[j]);
      }
    }
  }
#pragma unroll
  for (int j = 0; j < 8; ++j) Xp[c * 65 + 8 * r + j] = xp[j];
  __syncthreads();

  if (tid < BM) {
    float x = bu2[0];
#pragma unroll
    for (int cc = 0; cc < 32; ++cc) x += Xp[cc * 65 + tid];
    Xs[tid] = x;
  }
  __syncthreads();

  // ---- per-token top-4 + masked softmax: one wave per token ----
  const int wave = tid >> 6;
  const int lane = tid & 63;
  const size_t Moff_i = 4 * (size_t)M;
  const size_t Moff_k = 8 * (size_t)M;

  for (int t = wave; t < BM; t += 4) {
    float cur = Lg[t * 65 + lane];
    float topv[4];
    int topi[4];
#pragma unroll
    for (int s = 0; s < 4; ++s) {
      float mv = cur;
      int mi = lane;
#pragma unroll
      for (int off = 32; off >= 1; off >>= 1) {
        float ov = __shfl_xor(mv, off, 64);
        int oi = __shfl_xor(mi, off, 64);
        if (ov > mv || (ov == mv && oi < mi)) { mv = ov; mi = oi; }
      }
      topv[s] = mv;
      topi[s] = mi;
      if (lane == mi) cur = -INFINITY;   // stable: lowest index wins ties
    }
    if (lane == 0) {
      const int token = m0 + t;
      float x = Xs[t];
      float u = 1.f / (1.f + expf(-x));
      float kf = fmaf(3.f, u, 1.f);
      int kv = (int)rintf(kf);           // round-half-even == jnp.round
      kv = kv < 1 ? 1 : (kv > 4 ? 4 : kv);

      float w[4];
#pragma unroll
      for (int s = 0; s < 4; ++s) w[s] = (s < kv) ? topv[s] : 0.f;
      float mx = fmaxf(fmaxf(w[0], w[1]), fmaxf(w[2], w[3]));
      float e[4], sum = 0.f;
#pragma unroll
      for (int s = 0; s < 4; ++s) { e[s] = expf(w[s] - mx); sum += e[s]; }
      float inv = 1.f / sum;
#pragma unroll
      for (int s = 0; s < 4; ++s) {
        out[(size_t)token * 4 + s] = e[s] * inv;
        out[Moff_i + (size_t)token * 4 + s] = (s < kv) ? (float)topi[s] : -1.0f;
      }
      out[Moff_k + token] = (float)kv;
    }
  }
}

extern "C" void kernel_launch(void* const* d_in, const int* in_sizes, int n_in,
                              void* d_out, int out_size, void* d_ws, size_t ws_size,
                              hipStream_t stream) {
  (void)n_in; (void)d_ws; (void)ws_size; (void)out_size;
  const float* hs  = (const float*)d_in[0];
  const float* Wr  = (const float*)d_in[1];
  const float* br  = (const float*)d_in[2];
  const float* Wu1 = (const float*)d_in[3];
  const float* bu1 = (const float*)d_in[4];
  const float* Wu2 = (const float*)d_in[5];
  const float* bu2 = (const float*)d_in[6];
  float* out = (float*)d_out;

  const int M = in_sizes[0] / DIM;  // 32768
  dim3 grid(M / BM);                // 512 blocks, 2/CU resident (48 KB LDS)
  dim3 block(256);
  hipLaunchKernelGGL(ur_fused, grid, block, 0, stream,
                     hs, Wr, br, Wu1, bu1, Wu2, bu2, out, M);
}